// Round 5
// baseline (69.036 us; speedup 1.0000x reference)
//
#include <hip/hip_runtime.h>
#include <hip/hip_fp16.h>
#include <math.h>

#define BATCH     128
#define N_NODES   32768
#define N_CHILD   65536
#define NNZ_TOTAL 1048576

// ---------------------------------------------------------------------------
// Kernel 1: ex[c][b] = (half)exp(child_ll[b][c])  (tiled transpose via LDS)
// ---------------------------------------------------------------------------
__global__ __launch_bounds__(256) void exp_transpose_kernel(
    const float* __restrict__ child_ll, __half* __restrict__ ex) {
    __shared__ float tile[64][BATCH + 1];
    const int c0 = blockIdx.x * 64;
    const int t  = threadIdx.x;

    {
        const int cl = t & 63;
        const int b0 = t >> 6;  // 0..3
#pragma unroll
        for (int j = 0; j < BATCH / 4; ++j) {
            const int b = b0 + j * 4;
            tile[cl][b] = expf(child_ll[(size_t)b * N_CHILD + c0 + cl]);
        }
    }
    __syncthreads();

    {
        const int cl = t >> 4;         // 0..15
        const int b0 = (t & 15) * 8;   // 0..120
#pragma unroll
        for (int p = 0; p < 4; ++p) {
            const int c = p * 16 + cl;
            union { __half2 h[4]; uint4 u; } pk;
#pragma unroll
            for (int k = 0; k < 4; ++k)
                pk.h[k] = __half2{__float2half(tile[c][b0 + 2 * k]),
                                  __float2half(tile[c][b0 + 2 * k + 1])};
            *(uint4*)&ex[(size_t)(c0 + c) * BATCH + b0] = pk.u;
        }
    }
}

// ---------------------------------------------------------------------------
// Kernel 2: w[i] = exp(log_w[i])
// ---------------------------------------------------------------------------
__global__ __launch_bounds__(256) void exp_w_kernel(
    const float* __restrict__ log_w, float* __restrict__ w) {
    const int i = (blockIdx.x * 256 + threadIdx.x) * 4;
    float4 v = *(const float4*)&log_w[i];
    v.x = expf(v.x); v.y = expf(v.y); v.z = expf(v.z); v.w = expf(v.w);
    *(float4*)&w[i] = v;
}

// ---------------------------------------------------------------------------
// Kernel 3: row_start[r] = lower_bound(rows, r); rows is sorted.
// ---------------------------------------------------------------------------
__global__ __launch_bounds__(256) void row_starts_kernel(
    const int* __restrict__ rows, int* __restrict__ row_start) {
    const int r = blockIdx.x * blockDim.x + threadIdx.x;
    if (r > N_NODES) return;
    if (r == N_NODES) { row_start[r] = NNZ_TOTAL; return; }
    int lo = 0, hi = NNZ_TOTAL;
    while (lo < hi) {
        const int mid = (lo + hi) >> 1;
        if (rows[mid] < r) lo = mid + 1; else hi = mid;
    }
    row_start[r] = lo;
}

// ---------------------------------------------------------------------------
// Kernel 4: per-row sum, one wave per row. Each gather instr is uint4/lane
// with 16 lanes per nnz-row => 4 nnz per instruction. cols/w redistributed
// via ds_bpermute. 8 gathers (32 nnz, 2KB) in flight before first consume.
// ---------------------------------------------------------------------------
__global__ __launch_bounds__(256, 4) void sum_rows_kernel(
    const __half* __restrict__ ex, const float* __restrict__ w,
    const int* __restrict__ cols, const int* __restrict__ row_start,
    float* __restrict__ out) {
    const int wave = threadIdx.x >> 6;   // 0..3
    const int lane = threadIdx.x & 63;
    const int bid  = blockIdx.x;         // grid = 8192, %8==0
    const int rb   = (bid & 7) * (N_NODES / 4 / 8) + (bid >> 3);  // XCD swizzle
    const int r    = rb * 4 + wave;

    const int start = row_start[r];
    const int end   = row_start[r + 1];
    const char* exb = (const char*)ex;
    const unsigned bo = ((unsigned)lane & 15u) * 16u;  // byte off in 256B row
    const int pbase = (lane >> 4) * 4;                 // bpermute byte base

    float acc[8] = {0.f, 0.f, 0.f, 0.f, 0.f, 0.f, 0.f, 0.f};
    float wlane = 0.f;

    for (int base = start; base < end; base += 64) {
        const int  idx   = base + lane;
        const bool valid = idx < end;
        const int   c  = __builtin_nontemporal_load(&cols[valid ? idx : start]);
        const float wv = valid ? __builtin_nontemporal_load(&w[idx]) : 0.f;
        wlane += wv;
        const int seg = end - base;  // wave-uniform

#pragma unroll
        for (int h = 0; h < 2; ++h) {            // half = 32 nnz = 8 gathers
            const int hb = h * 32;
            if (hb >= seg) break;                // uniform

            int  ct[8];
            float wt[8];
            uint4 g[8];

            // Phase A: redistribute cols+weights (LDS pipe, back-to-back)
#pragma unroll
            for (int q = 0; q < 4; ++q) {        // q = 8-nnz granule
                if (hb + q * 8 < seg) {
#pragma unroll
                    for (int u = 0; u < 2; ++u) {
                        const int t = q * 2 + u;
                        const int pa = pbase + (hb + 4 * t) * 4;
                        ct[t] = __builtin_amdgcn_ds_bpermute(pa, c);
                        wt[t] = __uint_as_float(__builtin_amdgcn_ds_bpermute(
                            pa, __float_as_uint(wv)));
                    }
                }
            }
            // Phase B: issue all gathers (up to 8 dwordx4 in flight)
#pragma unroll
            for (int q = 0; q < 4; ++q) {
                if (hb + q * 8 < seg) {
#pragma unroll
                    for (int u = 0; u < 2; ++u) {
                        const int t = q * 2 + u;
                        g[t] = *(const uint4*)(exb +
                                ((size_t)(unsigned)ct[t] << 8) + bo);
                    }
                }
            }
            // Phase C: consume
#pragma unroll
            for (int q = 0; q < 4; ++q) {
                if (hb + q * 8 < seg) {
#pragma unroll
                    for (int u = 0; u < 2; ++u) {
                        const int t = q * 2 + u;
                        const __half2* hp = (const __half2*)&g[t];
#pragma unroll
                        for (int k = 0; k < 4; ++k) {
                            const float2 f = __half22float2(hp[k]);
                            acc[2 * k]     = fmaf(wt[t], f.x, acc[2 * k]);
                            acc[2 * k + 1] = fmaf(wt[t], f.y, acc[2 * k + 1]);
                        }
                    }
                }
            }
        }
    }

    // fold the 4 lane-groups (same batch samples) together
#pragma unroll
    for (int k = 0; k < 8; ++k) {
        acc[k] += __shfl_xor(acc[k], 16, 64);
        acc[k] += __shfl_xor(acc[k], 32, 64);
    }
    // wave-parallel normalization sum
    float wsum = wlane;
#pragma unroll
    for (int m = 1; m < 64; m <<= 1) wsum += __shfl_xor(wsum, m, 64);
    const float logz = logf(wsum);

    if (lane < 16) {
        const int b0 = lane * 8;
#pragma unroll
        for (int k = 0; k < 8; ++k)
            out[(size_t)(b0 + k) * N_NODES + r] = logf(acc[k]) - logz;
    }
}

// ---------------------------------------------------------------------------
extern "C" void kernel_launch(void* const* d_in, const int* in_sizes, int n_in,
                              void* d_out, int out_size, void* d_ws, size_t ws_size,
                              hipStream_t stream) {
    const float* child_ll = (const float*)d_in[0];
    const float* log_w    = (const float*)d_in[1];
    const int*   rows     = (const int*)d_in[2];
    const int*   cols     = (const int*)d_in[3];
    float*       out      = (float*)d_out;

    __half* ex        = (__half*)d_ws;                                        // 16.78 MB
    float*  w         = (float*)((char*)d_ws + (size_t)N_CHILD * BATCH * 2);  // 4 MB
    int*    row_start = (int*)((char*)w + (size_t)NNZ_TOTAL * 4);             // 128 KB

    exp_transpose_kernel<<<N_CHILD / 64, 256, 0, stream>>>(child_ll, ex);
    exp_w_kernel<<<NNZ_TOTAL / 1024, 256, 0, stream>>>(log_w, w);
    row_starts_kernel<<<(N_NODES + 256) / 256 + 1, 256, 0, stream>>>(rows, row_start);
    sum_rows_kernel<<<N_NODES / 4, 256, 0, stream>>>(ex, w, cols, row_start, out);
}